// Round 2
// baseline (241.688 us; speedup 1.0000x reference)
//
#include <hip/hip_runtime.h>

typedef unsigned int uint;
typedef unsigned short ushort;

// ---- bf16 helpers (used only for the tT LDS staging in fc_kernel) ----
__device__ __forceinline__ float b2f(ushort u) {
  union { uint i; float f; } v; v.i = ((uint)u) << 16; return v.f;
}
// round-to-nearest-even fp32 -> bf16
__device__ __forceinline__ ushort f2b(float f) {
  union { float f; uint i; } v; v.f = f;
  uint r = (v.i + 0x7fffu + ((v.i >> 16) & 1u)) >> 16;
  return (ushort)r;
}

// =====================================================================
// Kernel 1: per-thread conv pipeline (all fp32).
// x[128] f32 -> 12x12 grid (16 zero pad) -> conv3x3(1->3)+pool+relu
// -> conv3x3(3->6)+pool+relu -> h2[54] -> ws row of 64 f32 (10 zero pad)
// All activations in registers, fully unrolled.
// =====================================================================
__global__ __launch_bounds__(256) void conv_kernel(
    const float* __restrict__ x,
    const float* __restrict__ w1g, const float* __restrict__ b1g,
    const float* __restrict__ w2g, const float* __restrict__ b2g,
    float* __restrict__ h2ws) {
  const int s = blockIdx.x * 256 + threadIdx.x;
  const float* xs = x + (size_t)s * 128;

  // conv1 weights in registers (uniform loads)
  float w1[3][9], b1[3];
#pragma unroll
  for (int c = 0; c < 3; ++c) {
    b1[c] = b1g[c];
#pragma unroll
    for (int q = 0; q < 9; ++q) w1[c][q] = w1g[c * 9 + q];
  }

  float h1[3][6][6];
#pragma unroll
  for (int pr = 0; pr < 6; ++pr) {
    // padded g-rows 2pr-1 .. 2pr+2 ; R[i][jj] = g[r][jj-1], R[.][0]=R[.][13]=0
    float R[4][14];
#pragma unroll
    for (int i = 0; i < 4; ++i) {
      const int r = 2 * pr - 1 + i;
      R[i][0] = 0.f; R[i][13] = 0.f;
      if (r >= 0 && r <= 9) {
        const float4* p = (const float4*)(xs + 12 * r);  // 48r bytes, 16B aligned
        const float4 a = p[0], b = p[1], c = p[2];
        R[i][1] = a.x; R[i][2] = a.y; R[i][3] = a.z; R[i][4] = a.w;
        R[i][5] = b.x; R[i][6] = b.y; R[i][7] = b.z; R[i][8] = b.w;
        R[i][9] = c.x; R[i][10] = c.y; R[i][11] = c.z; R[i][12] = c.w;
      } else if (r == 10) {  // cols 0..7 = x[120..127], cols 8..11 = 0
        const float4* p = (const float4*)(xs + 120);
        const float4 a = p[0], b = p[1];
        R[i][1] = a.x; R[i][2] = a.y; R[i][3] = a.z; R[i][4] = a.w;
        R[i][5] = b.x; R[i][6] = b.y; R[i][7] = b.z; R[i][8] = b.w;
#pragma unroll
        for (int c2 = 9; c2 <= 12; ++c2) R[i][c2] = 0.f;
      } else {  // r == -1, 11, 12
#pragma unroll
        for (int c2 = 1; c2 <= 12; ++c2) R[i][c2] = 0.f;
      }
    }
#pragma unroll
    for (int ch = 0; ch < 3; ++ch) {
#pragma unroll
      for (int pc = 0; pc < 6; ++pc) {
        float m = -3.0e38f;
#pragma unroll
        for (int dr = 0; dr < 2; ++dr)
#pragma unroll
          for (int dc = 0; dc < 2; ++dc) {
            float a = 0.f;
#pragma unroll
            for (int ky = 0; ky < 3; ++ky)
#pragma unroll
              for (int kx = 0; kx < 3; ++kx)
                a = fmaf(w1[ch][ky * 3 + kx], R[dr + ky][2 * pc + dc + kx], a);
            m = fmaxf(m, a);
          }
        h1[ch][pr][pc] = fmaxf(m + b1[ch], 0.f);  // bias uniform: max then add
      }
    }
  }

  // conv2 (3->6) + pool + relu -> h2[54] (NCHW flatten: o*9 + qr*3 + qc)
  float h2[54];
#pragma unroll
  for (int o = 0; o < 6; ++o) {
    float w2[27];
#pragma unroll
    for (int q = 0; q < 27; ++q) w2[q] = w2g[o * 27 + q];
    const float bo = b2g[o];
#pragma unroll
    for (int qr = 0; qr < 3; ++qr)
#pragma unroll
      for (int qc = 0; qc < 3; ++qc) {
        float m = -3.0e38f;
#pragma unroll
        for (int dr = 0; dr < 2; ++dr)
#pragma unroll
          for (int dc = 0; dc < 2; ++dc) {
            float a = 0.f;
#pragma unroll
            for (int i = 0; i < 3; ++i)
#pragma unroll
              for (int ky = 0; ky < 3; ++ky)
#pragma unroll
                for (int kx = 0; kx < 3; ++kx) {
                  const int yy = 2 * qr + dr + ky - 1;
                  const int xx = 2 * qc + dc + kx - 1;
                  if (yy >= 0 && yy < 6 && xx >= 0 && xx < 6)  // folds at compile time
                    a = fmaf(w2[i * 9 + ky * 3 + kx], h1[i][yy][xx], a);
                }
            m = fmaxf(m, a);
          }
        h2[o * 9 + qr * 3 + qc] = fmaxf(m + bo, 0.f);
      }
  }

  // store h2 fp32, pad k=54..63 with zeros, 16x float4 stores
  float4* dst = (float4*)(h2ws + (size_t)s * 64);
#pragma unroll
  for (int i = 0; i < 16; ++i) {
    float4 v;
    v.x = (4 * i + 0 < 54) ? h2[4 * i + 0] : 0.f;
    v.y = (4 * i + 1 < 54) ? h2[4 * i + 1] : 0.f;
    v.z = (4 * i + 2 < 54) ? h2[4 * i + 2] : 0.f;
    v.w = (4 * i + 3 < 54) ? h2[4 * i + 3] : 0.f;
    dst[i] = v;
  }
}

// =====================================================================
// Kernel 2: fused FC (fp32 weights/activations; tT staged bf16).
// 64 samples/block, 256 threads.
// phase1: t = relu(h2 @ fc1_w^T + b)   [64 x 128], K=54
// phase2: out = t @ out_w^T + out_b    [64 x 128], K=128, out_w staged
//         in 4 chunks of 32 j-rows (fp32) through the union.
// LDS: 14688 + 28512 + 19456 + 1024 = 63680 B (< 64 KB).
// =====================================================================
__global__ __launch_bounds__(256) void fc_kernel(
    const float* __restrict__ h2ws,
    const float* __restrict__ fc1w, const float* __restrict__ fc1b,
    const float* __restrict__ outw, const float* __restrict__ outb,
    float* __restrict__ out) {
  __shared__ __align__(16) float h2T[54][68];   // [k][s]  14688 B
  __shared__ __align__(16) union {
    float w1T[54][132];                         // [k][j]  28512 B
    float wOT[32][132];                         // [jc][o] 16896 B
  } U;
  __shared__ __align__(16) ushort tT[128][76];  // [j][s] bf16, 19456 B
  __shared__ float fb1[128], ob[128];           // 1024 B

  const int t = threadIdx.x;
  const int s0 = blockIdx.x * 64;

  if (t < 128) { fb1[t] = fc1b[t]; ob[t] = outb[t]; }

  // stage h2 tile (64 samples x 64 f32), transpose to [k][s]
#pragma unroll
  for (int i = 0; i < 4; ++i) {
    const int f = t + i * 256;            // 0..1023 float4s
    const int si = f >> 4, kb = f & 15;   // 16 float4 per sample row
    const float4 v = *(const float4*)(h2ws + (size_t)(s0 + si) * 64 + kb * 4);
    const float vv[4] = {v.x, v.y, v.z, v.w};
#pragma unroll
    for (int m = 0; m < 4; ++m) {
      const int k = kb * 4 + m;
      if (k < 54) h2T[k][si] = vv[m];
    }
  }
  // stage fc1_w [128][54] -> w1T[k][j]; 6912 = 27*256 coalesced loads
#pragma unroll
  for (int i = 0; i < 27; ++i) {
    const int f = t + i * 256;
    const int j = f / 54;
    const int k = f - j * 54;
    U.w1T[k][j] = fc1w[f];
  }
  __syncthreads();

  const int sIdx = (t & 15) * 4;   // 4 samples
  const int j0 = (t >> 4) * 8;     // 8 features

  float acc[4][8];
#pragma unroll
  for (int ss = 0; ss < 4; ++ss)
#pragma unroll
    for (int jj = 0; jj < 8; ++jj) acc[ss][jj] = 0.f;

#pragma unroll 3
  for (int k = 0; k < 54; ++k) {
    const float4 av = *(const float4*)&h2T[k][sIdx];
    const float4 wa = *(const float4*)&U.w1T[k][j0];
    const float4 wb = *(const float4*)&U.w1T[k][j0 + 4];
    const float a[4] = {av.x, av.y, av.z, av.w};
    const float w[8] = {wa.x, wa.y, wa.z, wa.w, wb.x, wb.y, wb.z, wb.w};
#pragma unroll
    for (int ss = 0; ss < 4; ++ss)
#pragma unroll
      for (int jj = 0; jj < 8; ++jj)
        acc[ss][jj] = fmaf(a[ss], w[jj], acc[ss][jj]);
  }

  // bias + relu -> bf16 -> tT[j][s]  (the single quantization point)
#pragma unroll
  for (int jj = 0; jj < 8; ++jj) {
    const float bj = fb1[j0 + jj];
    ushort q[4];
#pragma unroll
    for (int ss = 0; ss < 4; ++ss) q[ss] = f2b(fmaxf(acc[ss][jj] + bj, 0.f));
    uint2 pv;
    pv.x = (uint)q[0] | ((uint)q[1] << 16);
    pv.y = (uint)q[2] | ((uint)q[3] << 16);
    *(uint2*)&tT[j0 + jj][sIdx] = pv;
  }

  float acc2[4][8];
#pragma unroll
  for (int ss = 0; ss < 4; ++ss)
#pragma unroll
    for (int jj = 0; jj < 8; ++jj) acc2[ss][jj] = 0.f;

  // phase2 over 4 chunks of 32 j-rows of out_w (fp32, through the union)
  for (int c = 0; c < 4; ++c) {
    __syncthreads();  // c==0: phase1 reads + tT writes done; c>0: chunk reads done
#pragma unroll
    for (int i = 0; i < 16; ++i) {
      const int f = t + i * 256;          // 0..4095
      const int o = f >> 5, jc = f & 31;  // coalesced over jc
      U.wOT[jc][o] = outw[o * 128 + c * 32 + jc];
    }
    __syncthreads();

#pragma unroll 4
    for (int jc = 0; jc < 32; ++jc) {
      const uint2 av = *(const uint2*)&tT[c * 32 + jc][sIdx];
      const float a[4] = {b2f((ushort)(av.x & 0xffffu)), b2f((ushort)(av.x >> 16)),
                          b2f((ushort)(av.y & 0xffffu)), b2f((ushort)(av.y >> 16))};
      const float4 wa = *(const float4*)&U.wOT[jc][j0];
      const float4 wb = *(const float4*)&U.wOT[jc][j0 + 4];
      const float w[8] = {wa.x, wa.y, wa.z, wa.w, wb.x, wb.y, wb.z, wb.w};
#pragma unroll
      for (int ss = 0; ss < 4; ++ss)
#pragma unroll
        for (int jj = 0; jj < 8; ++jj)
          acc2[ss][jj] = fmaf(a[ss], w[jj], acc2[ss][jj]);
    }
  }

  // + out_b, float4 global stores
#pragma unroll
  for (int ss = 0; ss < 4; ++ss) {
#pragma unroll
    for (int m = 0; m < 2; ++m) {
      float4 v;
      v.x = acc2[ss][4 * m + 0] + ob[j0 + 4 * m + 0];
      v.y = acc2[ss][4 * m + 1] + ob[j0 + 4 * m + 1];
      v.z = acc2[ss][4 * m + 2] + ob[j0 + 4 * m + 2];
      v.w = acc2[ss][4 * m + 3] + ob[j0 + 4 * m + 3];
      *(float4*)(out + (size_t)(s0 + sIdx + ss) * 128 + j0 + 4 * m) = v;
    }
  }
}

extern "C" void kernel_launch(void* const* d_in, const int* in_sizes, int n_in,
                              void* d_out, int out_size, void* d_ws, size_t ws_size,
                              hipStream_t stream) {
  const float* x    = (const float*)d_in[0];
  const float* w1   = (const float*)d_in[1];
  const float* b1   = (const float*)d_in[2];
  const float* w2   = (const float*)d_in[3];
  const float* b2   = (const float*)d_in[4];
  const float* fc1w = (const float*)d_in[5];
  const float* fc1b = (const float*)d_in[6];
  const float* outw = (const float*)d_in[7];
  const float* outb = (const float*)d_in[8];
  float* outp = (float*)d_out;
  float* ws   = (float*)d_ws;   // h2 staging: N x 64 f32 = 33.5 MB

  const int N = in_sizes[0] / 128;   // 131072

  conv_kernel<<<N / 256, 256, 0, stream>>>(x, w1, b1, w2, b2, ws);
  fc_kernel<<<N / 64, 256, 0, stream>>>(ws, fc1w, fc1b, outw, outb, outp);
}

// Round 3
// 169.026 us; speedup vs baseline: 1.4299x; 1.4299x over previous
//
#include <hip/hip_runtime.h>

typedef unsigned int uint;
typedef unsigned short ushort;

using bf16x8 = __attribute__((ext_vector_type(8))) short;
using f32x4  = __attribute__((ext_vector_type(4))) float;

// ---- bf16 helpers (bf16 = upper 16 bits of fp32) ----
__device__ __forceinline__ float b2f(ushort u) {
  union { uint i; float f; } v; v.i = ((uint)u) << 16; return v.f;
}
// round-to-nearest-even fp32 -> bf16
__device__ __forceinline__ ushort f2b(float f) {
  union { float f; uint i; } v; v.f = f;
  uint r = (v.i + 0x7fffu + ((v.i >> 16) & 1u)) >> 16;
  return (ushort)r;
}
__device__ __forceinline__ bf16x8 ldfrag(const ushort* p) {
  union { uint4 u; bf16x8 v; } x; x.u = *(const uint4*)p; return x.v;
}

// =====================================================================
// Kernel 1: per-thread conv pipeline, x fully register-resident.
// x[128] f32 -> 12x12 grid -> conv3x3(1->3)+pool+relu
// -> conv3x3(3->6)+pool+relu -> h2[54] -> ws row of 64 bf16 (pad 0)
// launch_bounds(256,1): 512-VGPR budget, no spill (live set ~290).
// =====================================================================
__global__ __launch_bounds__(256, 1) void conv_kernel(
    const float* __restrict__ x,
    const float* __restrict__ w1g, const float* __restrict__ b1g,
    const float* __restrict__ w2g, const float* __restrict__ b2g,
    ushort* __restrict__ h2ws) {
  const int s = blockIdx.x * 256 + threadIdx.x;
  const float* xs = x + (size_t)s * 128;

  // whole sample in registers: grid(r,c) = xv[12r+c] for 12r+c<128 else 0
  float xv[128];
#pragma unroll
  for (int i = 0; i < 32; ++i) {
    const float4 v = ((const float4*)xs)[i];
    xv[4 * i + 0] = v.x; xv[4 * i + 1] = v.y;
    xv[4 * i + 2] = v.z; xv[4 * i + 3] = v.w;
  }

  float w1[3][9], b1[3];
#pragma unroll
  for (int c = 0; c < 3; ++c) {
    b1[c] = b1g[c];
#pragma unroll
    for (int q = 0; q < 9; ++q) w1[c][q] = w1g[c * 9 + q];
  }

  float h1[3][6][6];
#pragma unroll
  for (int pr = 0; pr < 6; ++pr)
#pragma unroll
    for (int pc = 0; pc < 6; ++pc)
#pragma unroll
      for (int ch = 0; ch < 3; ++ch) {
        float m = -3.0e38f;
#pragma unroll
        for (int dr = 0; dr < 2; ++dr)
#pragma unroll
          for (int dc = 0; dc < 2; ++dc) {
            float a = 0.f;
#pragma unroll
            for (int ky = 0; ky < 3; ++ky)
#pragma unroll
              for (int kx = 0; kx < 3; ++kx) {
                const int r = 2 * pr + dr + ky - 1;
                const int c = 2 * pc + dc + kx - 1;
                if (r >= 0 && r < 12 && c >= 0 && c < 12 && (12 * r + c) < 128)
                  a = fmaf(w1[ch][ky * 3 + kx], xv[12 * r + c], a);  // folds
              }
            m = fmaxf(m, a);
          }
        h1[ch][pr][pc] = fmaxf(m + b1[ch], 0.f);
      }

  // conv2 (3->6) + pool + relu -> h2[54] (NCHW flatten: o*9 + qr*3 + qc)
  float h2[54];
#pragma unroll
  for (int o = 0; o < 6; ++o) {
    float w2[27];
#pragma unroll
    for (int q = 0; q < 27; ++q) w2[q] = w2g[o * 27 + q];
    const float bo = b2g[o];
#pragma unroll
    for (int qr = 0; qr < 3; ++qr)
#pragma unroll
      for (int qc = 0; qc < 3; ++qc) {
        float m = -3.0e38f;
#pragma unroll
        for (int dr = 0; dr < 2; ++dr)
#pragma unroll
          for (int dc = 0; dc < 2; ++dc) {
            float a = 0.f;
#pragma unroll
            for (int i = 0; i < 3; ++i)
#pragma unroll
              for (int ky = 0; ky < 3; ++ky)
#pragma unroll
                for (int kx = 0; kx < 3; ++kx) {
                  const int yy = 2 * qr + dr + ky - 1;
                  const int xx = 2 * qc + dc + kx - 1;
                  if (yy >= 0 && yy < 6 && xx >= 0 && xx < 6)  // folds
                    a = fmaf(w2[i * 9 + ky * 3 + kx], h1[i][yy][xx], a);
                }
            m = fmaxf(m, a);
          }
        h2[o * 9 + qr * 3 + qc] = fmaxf(m + bo, 0.f);
      }
  }

  // pack to bf16, pad k=54..63 with zeros (MFMA K=64 relies on this)
  uint pk[32];
#pragma unroll
  for (int q = 0; q < 27; ++q)
    pk[q] = (uint)f2b(h2[2 * q]) | ((uint)f2b(h2[2 * q + 1]) << 16);
#pragma unroll
  for (int q = 27; q < 32; ++q) pk[q] = 0u;
  uint4* dst = (uint4*)(h2ws + (size_t)s * 64);
#pragma unroll
  for (int i = 0; i < 8; ++i) {
    uint4 v; v.x = pk[4 * i]; v.y = pk[4 * i + 1];
    v.z = pk[4 * i + 2]; v.w = pk[4 * i + 3];
    dst[i] = v;
  }
}

// =====================================================================
// Kernel 2: fused FC via bf16 MFMA 16x16x32.
// 256 threads = 4 waves; 128 samples/block; wave w owns samples 32w..32w+31.
// phase1: t = relu(h2 @ fc1_w^T + b)  M=128 N=128 K=64 (zero-padded)
// phase2: out = t @ out_w^T + out_b   M=128 N=128 K=128
// LDS union: {h2s+w1s 36.9KB} / {tA+owB 69.6KB} + biases -> 70.7 KB,
// 2 blocks/CU. All tiles 16B-aligned rows; strides 72/136 (2-way only).
// =====================================================================
__global__ __launch_bounds__(256, 2) void fc_kernel(
    const ushort* __restrict__ h2ws,
    const float* __restrict__ fc1w, const float* __restrict__ fc1b,
    const float* __restrict__ outw, const float* __restrict__ outb,
    float* __restrict__ out) {
  __shared__ __align__(16) union {
    struct { ushort h2s[128][72]; ushort w1s[128][72]; } p1;   // 36864 B
    struct { ushort tA[128][136]; ushort owB[128][136]; } p2;  // 69632 B
  } U;
  __shared__ float fb1[128], ob[128];

  const int t = threadIdx.x;
  const int s0 = blockIdx.x * 128;
  const int lane = t & 63, wv = t >> 6;
  const int quad = lane >> 4, lm = lane & 15;

  if (t < 128) { fb1[t] = fc1b[t]; ob[t] = outb[t]; }

  // stage h2s: 128 samples x 64 bf16 (k 54..63 already zero in ws)
#pragma unroll
  for (int i = 0; i < 4; ++i) {
    const int f = t + 256 * i;            // 0..1023 uint4s
    const int si = f >> 3, kb = f & 7;
    *(uint4*)&U.p1.h2s[si][kb * 8] =
        *(const uint4*)(h2ws + (size_t)(s0 + si) * 64 + kb * 8);
  }
  // stage fc1_w [128][54] fp32 -> bf16 B-layout [n][k]
#pragma unroll
  for (int i = 0; i < 27; ++i) {
    const int f = t + 256 * i;            // 0..6911
    const int n = f / 54, k = f - 54 * n;
    U.p1.w1s[n][k] = f2b(fc1w[f]);
  }
  // zero-pad w1s k=54..63 (byte offset 108, dword aligned)
  if (t < 128) {
    uint* p = (uint*)&U.p1.w1s[t][54];
#pragma unroll
    for (int q = 0; q < 5; ++q) p[q] = 0u;
  }
  __syncthreads();

  // ---- phase1 MFMA: acc[mt][nt] = h2[32wv+16mt ..][k] * w1[16nt ..][k]
  f32x4 acc[2][8];
#pragma unroll
  for (int mt = 0; mt < 2; ++mt)
#pragma unroll
    for (int nt = 0; nt < 8; ++nt) acc[mt][nt] = (f32x4){0.f, 0.f, 0.f, 0.f};

#pragma unroll
  for (int kk = 0; kk < 2; ++kk) {
    const int ko = kk * 32 + quad * 8;
    bf16x8 a[2], b[8];
#pragma unroll
    for (int mt = 0; mt < 2; ++mt)
      a[mt] = ldfrag(&U.p1.h2s[32 * wv + 16 * mt + lm][ko]);
#pragma unroll
    for (int nt = 0; nt < 8; ++nt)
      b[nt] = ldfrag(&U.p1.w1s[16 * nt + lm][ko]);
#pragma unroll
    for (int mt = 0; mt < 2; ++mt)
#pragma unroll
      for (int nt = 0; nt < 8; ++nt)
        acc[mt][nt] = __builtin_amdgcn_mfma_f32_16x16x32_bf16(
            a[mt], b[nt], acc[mt][nt], 0, 0, 0);
  }
  __syncthreads();  // phase1 LDS reads complete before union overwrite

  // t = relu(acc + b) -> bf16 -> tA (A-layout rows=samples, cols=j)
#pragma unroll
  for (int mt = 0; mt < 2; ++mt)
#pragma unroll
    for (int nt = 0; nt < 8; ++nt) {
      const int col = 16 * nt + lm;
      const float bj = fb1[col];
#pragma unroll
      for (int r = 0; r < 4; ++r) {
        const int row = 32 * wv + 16 * mt + quad * 4 + r;
        U.p2.tA[row][col] = f2b(fmaxf(acc[mt][nt][r] + bj, 0.f));
      }
    }
  // stage out_w [128][128] fp32 -> bf16 B-layout owB[o][j]
#pragma unroll
  for (int i = 0; i < 16; ++i) {
    const int f = t + 256 * i;            // 0..4095 float4s
    const int o = f >> 5, j4 = (f & 31) * 4;
    const float4 v = *(const float4*)(outw + o * 128 + j4);
    uint2 pv;
    pv.x = (uint)f2b(v.x) | ((uint)f2b(v.y) << 16);
    pv.y = (uint)f2b(v.z) | ((uint)f2b(v.w) << 16);
    *(uint2*)&U.p2.owB[o][j4] = pv;
  }
  __syncthreads();

  // ---- phase2 MFMA: out = t @ out_w^T
  f32x4 acc2[2][8];
#pragma unroll
  for (int mt = 0; mt < 2; ++mt)
#pragma unroll
    for (int nt = 0; nt < 8; ++nt) acc2[mt][nt] = (f32x4){0.f, 0.f, 0.f, 0.f};

#pragma unroll
  for (int kk = 0; kk < 4; ++kk) {
    const int ko = kk * 32 + quad * 8;
    bf16x8 a[2], b[8];
#pragma unroll
    for (int mt = 0; mt < 2; ++mt)
      a[mt] = ldfrag(&U.p2.tA[32 * wv + 16 * mt + lm][ko]);
#pragma unroll
    for (int nt = 0; nt < 8; ++nt)
      b[nt] = ldfrag(&U.p2.owB[16 * nt + lm][ko]);
#pragma unroll
    for (int mt = 0; mt < 2; ++mt)
#pragma unroll
      for (int nt = 0; nt < 8; ++nt)
        acc2[mt][nt] = __builtin_amdgcn_mfma_f32_16x16x32_bf16(
            a[mt], b[nt], acc2[mt][nt], 0, 0, 0);
  }

  // epilogue: + out_b, fp32 stores (C layout: col=lm, row=quad*4+r)
#pragma unroll
  for (int mt = 0; mt < 2; ++mt)
#pragma unroll
    for (int nt = 0; nt < 8; ++nt) {
      const int col = 16 * nt + lm;
      const float bo = ob[col];
#pragma unroll
      for (int r = 0; r < 4; ++r) {
        const int srow = s0 + 32 * wv + 16 * mt + quad * 4 + r;
        out[(size_t)srow * 128 + col] = acc2[mt][nt][r] + bo;
      }
    }
}

extern "C" void kernel_launch(void* const* d_in, const int* in_sizes, int n_in,
                              void* d_out, int out_size, void* d_ws, size_t ws_size,
                              hipStream_t stream) {
  const float* x    = (const float*)d_in[0];
  const float* w1   = (const float*)d_in[1];
  const float* b1   = (const float*)d_in[2];
  const float* w2   = (const float*)d_in[3];
  const float* b2   = (const float*)d_in[4];
  const float* fc1w = (const float*)d_in[5];
  const float* fc1b = (const float*)d_in[6];
  const float* outw = (const float*)d_in[7];
  const float* outb = (const float*)d_in[8];
  float* outp = (float*)d_out;
  ushort* ws  = (ushort*)d_ws;   // h2 staging: N x 64 bf16 = 16.8 MB

  const int N = in_sizes[0] / 128;   // 131072

  conv_kernel<<<N / 256, 256, 0, stream>>>(x, w1, b1, w2, b2, ws);
  fc_kernel<<<N / 128, 256, 0, stream>>>(ws, fc1w, fc1b, outw, outb, outp);
}